// Round 6
// baseline (472.729 us; speedup 1.0000x reference)
//
#include <hip/hip_runtime.h>
#include <cstdint>
#include <cstddef>

using short8  = __attribute__((ext_vector_type(8))) short;
using floatx4 = __attribute__((ext_vector_type(4))) float;

#define DEV __device__ __forceinline__

DEV float u2f(unsigned short u){
  union { unsigned int i; float f; } c; c.i = ((unsigned int)u) << 16; return c.f;
}
DEV unsigned short f2u(float f){
  union { float f; unsigned int i; } c; c.f = f;
  unsigned int i = c.i;
  i += 0x7fffu + ((i >> 16) & 1u);   // RNE to bf16 (finite values only here)
  return (unsigned short)(i >> 16);
}
DEV float sigmoidf_(float x){ return 1.0f / (1.0f + __expf(-x)); }
DEV float siluf_(float x){ return x / (1.0f + __expf(-x)); }

// async global->LDS, 16 B per lane; LDS dest must be wave-uniform base + lane*16
#define ASYNC_LD16(g, l) __builtin_amdgcn_global_load_lds( \
    (const __attribute__((address_space(1))) unsigned int*)(g), \
    (__attribute__((address_space(3))) unsigned int*)(l), 16, 0, 0)

#define MFMA_BF16 __builtin_amdgcn_mfma_f32_16x16x32_bf16

// raw barrier, opaque to the compiler's waitcnt-insertion pass: no implicit
// vmcnt(0) drain can be attached (R3-proven: 122us -> 53.8us on gemm256).
#define SBAR() asm volatile("s_barrier" ::: "memory")
#define LGKM0() asm volatile("s_waitcnt lgkmcnt(0)" ::: "memory")

// problem-fixed sizes: T=2048 S=2048 B=4 E=1024 Z=128
constexpr float SCALING = 0.088388347648318447f; // 128^-0.5

// ---------------------------------------------------------------- fused casts + memset
// blocks [0,8192): query rows -> qbf; [8192,16384): key rows -> kbr (batch de-interleave)
// [16384,18560): Wq; [18560,18688): Wk; [18688,19712): Wv; [19712,20736): Wh
// block 20736: rs = 0 (8192 floats)
__global__ __launch_bounds__(256) void cast_all(
    const float* __restrict__ q, const float* __restrict__ k,
    const float* __restrict__ Wq, const float* __restrict__ Wk,
    const float* __restrict__ Wv, const float* __restrict__ Wh,
    unsigned short* __restrict__ qo, unsigned short* __restrict__ ko,
    unsigned short* __restrict__ oq, unsigned short* __restrict__ ok,
    unsigned short* __restrict__ ov, unsigned short* __restrict__ oh,
    float* __restrict__ rs)
{
  const int bid = blockIdx.x;
  const int e = threadIdx.x * 4;
  if (bid == 20736) {
    float4 z = {0.f, 0.f, 0.f, 0.f};
    #pragma unroll
    for (int i = 0; i < 8; i++)
      *(float4*)(rs + (threadIdx.x * 8 + i) * 4) = z;
    return;
  }
  const float* src; unsigned short* dst;
  if (bid < 8192) {
    src = q + (long long)bid * 1024;
    dst = qo + (long long)bid * 1024;
  } else if (bid < 16384) {
    const int m = bid - 8192;
    const int s = m >> 2, b = m & 3;
    src = k + (long long)m * 1024;
    dst = ko + ((long long)b * 2048 + s) * 1024;
  } else if (bid < 18560) { src = Wq + (long long)(bid-16384) * 1024; dst = oq + (long long)(bid-16384) * 1024; }
  else if (bid < 18688)   { src = Wk + (long long)(bid-18560) * 1024; dst = ok + (long long)(bid-18560) * 1024; }
  else if (bid < 19712)   { src = Wv + (long long)(bid-18688) * 1024; dst = ov + (long long)(bid-18688) * 1024; }
  else                    { src = Wh + (long long)(bid-19712) * 1024; dst = oh + (long long)(bid-19712) * 1024; }
  const float4 v = *(const float4*)(src + e);
  ushort4 o; o.x=f2u(v.x); o.y=f2u(v.y); o.z=f2u(v.z); o.w=f2u(v.w);
  *(ushort4*)(dst + e) = o;
}

// ---------------------------------------------------------------- R0 GEMM, occupancy-freed
// C[M,N] = A[M,K] * B[N,K]^T, bf16 in, fp32 acc. 128x128 tile, BK=64,
// single-buffer K-loop, 256 thr = 4 waves (2x2), wave 64x64 via 4x4 MFMA.
// R6: __launch_bounds__(256, 4) — R0's (256,2) measured 22% occupancy (~2
// blocks/CU) despite VGPR 60 / LDS 32KB allowing 5; theory: 2nd arg acts as
// an effective waves/EU cap. 4 waves/EU = 4 blocks/CU; m97 evidence: this
// single-buffer structure reaches ~874 TF when multi-block overlap is free.
// EPI: 2 = v proj SWAPPED (A=Wv, B=kbr): gm=e, gn=(b,s) -> vT coalesced
//      3 = exp epilogue: P~ = exp(v*SCALING) bf16 + atomic fp32 rowsum (f0)
//      4 = PV: h = acc/rowsum, out = h*r (bf16)
//      5 = Wh proj -> out = q + u*(tanh(.)-q)  (fp32; u bf16 via rmul)
template<int EPI>
__global__ __launch_bounds__(256, 4)
void gemm_bt(const unsigned short* __restrict__ A, long long bsA, int lda,
             const unsigned short* __restrict__ Bm, long long bsB, int ldb,
             int K,
             const float* __restrict__ bias,
             float* __restrict__ f0,
             unsigned short* __restrict__ b0,
             const unsigned short* __restrict__ rmul,
             const float* __restrict__ qin)
{
  __shared__ __align__(16) unsigned short As[128][64];
  __shared__ __align__(16) unsigned short Bs[128][64];

  const int tid = threadIdx.x;
  const int bm = blockIdx.x, bn = blockIdx.y, bz = blockIdx.z;
  const unsigned short* Ag = A  + (long long)bz * bsA;
  const unsigned short* Bg = Bm + (long long)bz * bsB;
  const int row0 = bm * 128;
  const int col0 = bn * 128;

  const int lane = tid & 63;
  const int wv   = tid >> 6;
  const int wm   = (wv & 1) * 64;
  const int wn   = (wv >> 1) * 64;
  const int lr   = lane & 15;
  const int lq   = lane >> 4;
  const int r7   = lr & 7;

  const unsigned short* gA[4]; const unsigned short* gB[4];
  unsigned short* lA[4]; unsigned short* lB[4];
  #pragma unroll
  for (int i = 0; i < 4; i++) {
    const int c  = tid + i * 256;
    const int rr = c >> 3;
    const int gc = (c & 7) ^ (rr & 7);
    gA[i] = Ag + (long long)(row0 + rr) * lda + gc * 8;
    gB[i] = Bg + (long long)(col0 + rr) * ldb + gc * 8;
    lA[i] = &As[0][0] + c * 8;
    lB[i] = &Bs[0][0] + c * 8;
  }

  floatx4 acc[4][4];
  const floatx4 zero = {0.f, 0.f, 0.f, 0.f};
  #pragma unroll
  for (int i = 0; i < 4; i++)
    #pragma unroll
    for (int j = 0; j < 4; j++) acc[i][j] = zero;

  for (int kt = 0; kt < K; kt += 64) {
    #pragma unroll
    for (int i = 0; i < 4; i++) {
      ASYNC_LD16(gA[i] + kt, lA[i]);
      ASYNC_LD16(gB[i] + kt, lB[i]);
    }
    __syncthreads();
    #pragma unroll
    for (int ks = 0; ks < 64; ks += 32) {
      const int k8 = ks >> 3;
      short8 af[4], bfv[4];
      #pragma unroll
      for (int i = 0; i < 4; i++) {
        const int sc = (lq + k8) ^ r7;
        af[i]  = *(const short8*)(&As[wm + i*16 + lr][sc * 8]);
        bfv[i] = *(const short8*)(&Bs[wn + i*16 + lr][sc * 8]);
      }
      #pragma unroll
      for (int mi = 0; mi < 4; mi++)
        #pragma unroll
        for (int ni = 0; ni < 4; ni++)
          acc[mi][ni] = MFMA_BF16(af[mi], bfv[ni], acc[mi][ni], 0, 0, 0);
    }
    __syncthreads();
  }

  #pragma unroll
  for (int mi = 0; mi < 4; mi++) {
    float s4[4];
    float iv[4];
    if constexpr (EPI == 3) {
      #pragma unroll
      for (int r = 0; r < 4; r++) s4[r] = 0.f;
    }
    if constexpr (EPI == 4) {
      #pragma unroll
      for (int r = 0; r < 4; r++) {
        const int gm = row0 + wm + mi * 16 + lq * 4 + r;
        iv[r] = 1.0f / f0[(long long)bz * 2048 + gm];
      }
    }
    #pragma unroll
    for (int ni = 0; ni < 4; ni++) {
      #pragma unroll
      for (int r = 0; r < 4; r++) {
        const int gm = row0 + wm + mi * 16 + lq * 4 + r;
        const int gn = col0 + wn + ni * 16 + lr;
        float v = acc[mi][ni][r];
        if constexpr (EPI == 2) {
          v += bias[gm];                                               // bias by e-row
          const int b = gn >> 11, s = gn & 2047;
          b0[((long long)b * 1024 + gm) * 2048 + s] = f2u(siluf_(v));  // v^T coalesced
        } else if constexpr (EPI == 3) {
          const float e = __expf(v * SCALING);
          b0[(long long)bz * 2048 * 2048 + (long long)gm * 2048 + gn] = f2u(e);
          s4[r] += e;
        } else if constexpr (EPI == 4) {
          const long long idx = ((long long)gm * 4 + bz) * 1024 + gn;  // (t,b,e)
          b0[idx] = f2u(v * iv[r] * u2f(rmul[idx]));                   // h*r
        } else { // EPI == 5
          const long long idx = (long long)gm * 1024 + gn;
          const float tv = tanhf(v + bias[gn]);
          const float qv = qin[idx];
          f0[idx] = qv + u2f(rmul[idx]) * (tv - qv);                   // final out
        }
      }
    }
    if constexpr (EPI == 3) {
      #pragma unroll
      for (int r = 0; r < 4; r++) {
        float s = s4[r];
        #pragma unroll
        for (int m2 = 8; m2 >= 1; m2 >>= 1) s += __shfl_xor(s, m2); // 16-lane group
        if (lr == 0) {
          const int gm = row0 + wm + mi * 16 + lq * 4 + r;
          atomicAdd(f0 + (long long)bz * 2048 + gm, s);
        }
      }
    }
  }
}

// ---------------------------------------------------------------- merged N=128 GEMMs
// z=0: qpj = silu(qbf @ WqSlice^T + bq[2048:])*gamma0+beta0   (q projection)
// z=1: kpj = silu(kbr @ Wk^T + bk)*gamma1+beta1                (k projection)
__global__ __launch_bounds__(256, 4)
void gemm_nz128(const unsigned short* __restrict__ A0, const unsigned short* __restrict__ A1,
                const unsigned short* __restrict__ B0, const unsigned short* __restrict__ B1,
                const float* __restrict__ bi0, const float* __restrict__ bi1,
                const float* __restrict__ g0,  const float* __restrict__ g1,
                const float* __restrict__ be0, const float* __restrict__ be1,
                unsigned short* __restrict__ o0, unsigned short* __restrict__ o1)
{
  __shared__ __align__(16) unsigned short As[128][64];
  __shared__ __align__(16) unsigned short Bs[128][64];

  const int tid = threadIdx.x;
  const int bm = blockIdx.x;
  const int z  = blockIdx.z;
  const unsigned short* Ag = z ? A1 : A0;
  const unsigned short* Bg = z ? B1 : B0;
  const float* bias = z ? bi1 : bi0;
  const float* gam  = z ? g1  : g0;
  const float* bet  = z ? be1 : be0;
  unsigned short* ob = z ? o1 : o0;
  const int row0 = bm * 128;

  const int lane = tid & 63;
  const int wv   = tid >> 6;
  const int wm   = (wv & 1) * 64;
  const int wn   = (wv >> 1) * 64;
  const int lr   = lane & 15;
  const int lq   = lane >> 4;
  const int r7   = lr & 7;

  const unsigned short* gA[4]; const unsigned short* gB[4];
  unsigned short* lA[4]; unsigned short* lB[4];
  #pragma unroll
  for (int i = 0; i < 4; i++) {
    const int c  = tid + i * 256;
    const int rr = c >> 3;
    const int gc = (c & 7) ^ (rr & 7);
    gA[i] = Ag + (long long)(row0 + rr) * 1024 + gc * 8;
    gB[i] = Bg + (long long)rr * 1024 + gc * 8;
    lA[i] = &As[0][0] + c * 8;
    lB[i] = &Bs[0][0] + c * 8;
  }

  floatx4 acc[4][4];
  const floatx4 zero = {0.f, 0.f, 0.f, 0.f};
  #pragma unroll
  for (int i = 0; i < 4; i++)
    #pragma unroll
    for (int j = 0; j < 4; j++) acc[i][j] = zero;

  for (int kt = 0; kt < 1024; kt += 64) {
    #pragma unroll
    for (int i = 0; i < 4; i++) {
      ASYNC_LD16(gA[i] + kt, lA[i]);
      ASYNC_LD16(gB[i] + kt, lB[i]);
    }
    __syncthreads();
    #pragma unroll
    for (int ks = 0; ks < 64; ks += 32) {
      const int k8 = ks >> 3;
      short8 af[4], bfv[4];
      #pragma unroll
      for (int i = 0; i < 4; i++) {
        const int sc = (lq + k8) ^ r7;
        af[i]  = *(const short8*)(&As[wm + i*16 + lr][sc * 8]);
        bfv[i] = *(const short8*)(&Bs[wn + i*16 + lr][sc * 8]);
      }
      #pragma unroll
      for (int mi = 0; mi < 4; mi++)
        #pragma unroll
        for (int ni = 0; ni < 4; ni++)
          acc[mi][ni] = MFMA_BF16(af[mi], bfv[ni], acc[mi][ni], 0, 0, 0);
    }
    __syncthreads();
  }

  #pragma unroll
  for (int mi = 0; mi < 4; mi++)
    #pragma unroll
    for (int ni = 0; ni < 4; ni++)
      #pragma unroll
      for (int r = 0; r < 4; r++) {
        const int gm = row0 + wm + mi * 16 + lq * 4 + r;
        const int gn = wn + ni * 16 + lr;
        float v = acc[mi][ni][r] + bias[gn];
        ob[(long long)gm * 128 + gn] = f2u(siluf_(v) * gam[gn] + bet[gn]);
      }
}

// ---------------------------------------------------------------- 256x256 counted-vmcnt GEMM (g0)
// Control: unchanged from R5 (51.2 us measured). Raw SBAR + counted vmcnt(8).
__global__ __launch_bounds__(512, 2)
void gemm256(const unsigned short* __restrict__ A, int lda,
             const unsigned short* __restrict__ Bm, int ldb,
             int K,
             const float* __restrict__ bias,
             float* __restrict__ f0,
             unsigned short* __restrict__ b0)
{
  __shared__ __align__(16) unsigned short Ls[65536]; // 128 KiB: [buf2][A 16384 | B 16384]

  const int tid = threadIdx.x;
  const int bm = blockIdx.x, bn = blockIdx.y;
  const int row0 = bm * 256;
  const int col0 = bn * 256;

  const int lane = tid & 63;
  const int wv   = tid >> 6;
  const int wr   = (wv >> 2) * 128;
  const int wc   = (wv & 3) * 64;
  const int lr   = lane & 15;
  const int lq   = lane >> 4;
  const int r7   = lr & 7;

  const int rr0 = tid >> 3;
  const int swz = ((tid & 7) ^ (rr0 & 7)) * 8;
  const unsigned short* gA0 = A  + (long long)(row0 + rr0) * lda + swz;
  const unsigned short* gB0 = Bm + (long long)(col0 + rr0) * ldb + swz;
  const long long sA64 = 64LL * lda, sB64 = 64LL * ldb;
  unsigned short* lA0 = &Ls[0]     + tid * 8;
  unsigned short* lB0 = &Ls[16384] + tid * 8;

  floatx4 acc[8][4];
  const floatx4 zero = {0.f, 0.f, 0.f, 0.f};
  #pragma unroll
  for (int i = 0; i < 8; i++)
    #pragma unroll
    for (int j = 0; j < 4; j++) acc[i][j] = zero;

  const int NT = K >> 6;

  #pragma unroll
  for (int i = 0; i < 4; i++) ASYNC_LD16(gA0 + i * sA64,      lA0 + i * 4096);
  #pragma unroll
  for (int i = 0; i < 4; i++) ASYNC_LD16(gB0 + i * sB64,      lB0 + i * 4096);
  #pragma unroll
  for (int i = 0; i < 4; i++) ASYNC_LD16(gA0 + i * sA64 + 64, lA0 + i * 4096 + 32768);
  #pragma unroll
  for (int i = 0; i < 4; i++) ASYNC_LD16(gB0 + i * sB64 + 64, lB0 + i * 4096 + 32768);
  asm volatile("s_waitcnt vmcnt(8)" ::: "memory");
  SBAR();

  for (int t = 0; t < NT; ++t) {
    const int cb = (t & 1) << 15;
    const unsigned short* Ab = &Ls[cb];
    const unsigned short* Bb = &Ls[cb + 16384];
    const bool st = (t + 2) < NT;
    const int kt2 = (t + 2) << 6;

    short8 afA[4][2], afB[4][2], bf01[2][2], bf23[2][2];

    // ---- ph1+ph2 (fused): 16 ds_reads; 32 MFMA Q(0-3, 0-3)
    #pragma unroll
    for (int mi = 0; mi < 4; mi++)
      #pragma unroll
      for (int k = 0; k < 2; k++)
        afA[mi][k] = *(const short8*)(Ab + (wr + mi*16 + lr) * 64 + (((k<<2) + lq) ^ r7) * 8);
    #pragma unroll
    for (int ni = 0; ni < 2; ni++)
      #pragma unroll
      for (int k = 0; k < 2; k++)
        bf01[ni][k] = *(const short8*)(Bb + (wc + ni*16 + lr) * 64 + (((k<<2) + lq) ^ r7) * 8);
    #pragma unroll
    for (int ni = 0; ni < 2; ni++)
      #pragma unroll
      for (int k = 0; k < 2; k++)
        bf23[ni][k] = *(const short8*)(Bb + (wc + (ni+2)*16 + lr) * 64 + (((k<<2) + lq) ^ r7) * 8);
    __builtin_amdgcn_s_setprio(1);
    #pragma unroll
    for (int mi = 0; mi < 4; mi++)
      #pragma unroll
      for (int ni = 0; ni < 2; ni++)
        #pragma unroll
        for (int k = 0; k < 2; k++)
          acc[mi][ni] = MFMA_BF16(afA[mi][k], bf01[ni][k], acc[mi][ni], 0, 0, 0);
    #pragma unroll
    for (int mi = 0; mi < 4; mi++)
      #pragma unroll
      for (int ni = 0; ni < 2; ni++)
        #pragma unroll
        for (int k = 0; k < 2; k++)
          acc[mi][ni+2] = MFMA_BF16(afA[mi][k], bf23[ni][k], acc[mi][ni+2], 0, 0, 0);
    __builtin_amdgcn_s_setprio(0);
    LGKM0();
    SBAR();   // all B-slot reads (bf01, bf23) drained in every wave

    // ---- ph3: 8 ds_reads (afB mi4-7); stage B(t+2); MFMA Q(4-7, 0-1)
    #pragma unroll
    for (int mi = 0; mi < 4; mi++)
      #pragma unroll
      for (int k = 0; k < 2; k++)
        afB[mi][k] = *(const short8*)(Ab + (wr + (mi+4)*16 + lr) * 64 + (((k<<2) + lq) ^ r7) * 8);
    if (st) {
      #pragma unroll
      for (int i = 0; i < 4; i++) ASYNC_LD16(gB0 + i * sB64 + kt2, lB0 + i * 4096 + cb);
    }
    __builtin_amdgcn_s_setprio(1);
    #pragma unroll
    for (int mi = 0; mi < 4; mi++)
      #pragma unroll
      for (int ni = 0; ni < 2; ni++)
        #pragma unroll
        for (int k = 0; k < 2; k++)
          acc[mi+4][ni] = MFMA_BF16(afB[mi][k], bf01[ni][k], acc[mi+4][ni], 0, 0, 0);
    __builtin_amdgcn_s_setprio(0);
    LGKM0();
    SBAR();   // all A-slot reads (afA, afB) drained in every wave

    // ---- ph4: stage A(t+2); MFMA Q(4-7, 2-3); boundary
    if (st) {
      #pragma unroll
      for (int i = 0; i < 4; i++) ASYNC_LD16(gA0 + i * sA64 + kt2, lA0 + i * 4096 + cb);
    }
    __builtin_amdgcn_s_setprio(1);
    #pragma unroll
    for (int mi = 0; mi < 4; mi++)
      #pragma unroll
      for (int ni = 0; ni < 2; ni++)
        #pragma unroll
        for (int k = 0; k < 2; k++)
          acc[mi+4][ni+2] = MFMA_BF16(afB[mi][k], bf23[ni][k], acc[mi+4][ni+2], 0, 0, 0);
    __builtin_amdgcn_s_setprio(0);
    if (st) { asm volatile("s_waitcnt vmcnt(8)" ::: "memory"); }
    else    { asm volatile("s_waitcnt vmcnt(0)" ::: "memory"); }
    SBAR();
  }

  // epilogue (EPI0, N=2048: u for gn<1024 else r)
  #pragma unroll
  for (int mi = 0; mi < 8; mi++)
    #pragma unroll
    for (int ni = 0; ni < 4; ni++)
      #pragma unroll
      for (int r = 0; r < 4; r++) {
        const int gm = row0 + wr + mi * 16 + lq * 4 + r;
        const int gn = col0 + wc + ni * 16 + lr;
        float v = acc[mi][ni][r] + bias[gn];
        if (gn < 1024) {
          ((unsigned short*)f0)[(long long)gm * 1024 + gn] = f2u(sigmoidf_(v)); // u bf16
        } else {
          b0[(long long)gm * 1024 + (gn - 1024)] = f2u(siluf_(v));    // r
        }
      }
}

// ---------------------------------------------------------------- launch
extern "C" void kernel_launch(void* const* d_in, const int* in_sizes, int n_in,
                              void* d_out, int out_size, void* d_ws, size_t ws_size,
                              hipStream_t stream)
{
  (void)in_sizes; (void)n_in; (void)out_size; (void)ws_size;
  const float* query = (const float*)d_in[0];
  const float* key   = (const float*)d_in[1];
  const float* Wq    = (const float*)d_in[2];
  const float* bq    = (const float*)d_in[3];
  const float* Wk    = (const float*)d_in[4];
  const float* bk    = (const float*)d_in[5];
  const float* Wv    = (const float*)d_in[6];
  const float* bv    = (const float*)d_in[7];
  const float* Wh    = (const float*)d_in[8];
  const float* bh    = (const float*)d_in[9];
  const float* gamma = (const float*)d_in[10];
  const float* beta  = (const float*)d_in[11];
  float* out = (float*)d_out;

  char* p = (char*)d_ws;
  auto take = [&](size_t bytes) -> char* {
    char* r = p; p += (bytes + 255) & ~(size_t)255; return r;
  };
  unsigned short* qbf = (unsigned short*)take(8192ULL * 1024 * 2); // query bf16 (T*B,E)
  unsigned short* kbr = (unsigned short*)take(8192ULL * 1024 * 2); // key bf16 [B][S][E]
  unsigned short* Wqb = (unsigned short*)take(2176ULL * 1024 * 2);
  unsigned short* Wkb = (unsigned short*)take(128ULL  * 1024 * 2);
  unsigned short* Wvb = (unsigned short*)take(1024ULL * 1024 * 2);
  unsigned short* Whb = (unsigned short*)take(1024ULL * 1024 * 2);
  unsigned short* ub  = (unsigned short*)take(8192ULL * 1024 * 2); // u gate bf16
  unsigned short* rbf = (unsigned short*)take(8192ULL * 1024 * 2); // r bf16
  unsigned short* qpj = (unsigned short*)take(8192ULL * 128 * 2);  // q (T,B,Z)
  unsigned short* kpj = (unsigned short*)take(8192ULL * 128 * 2);  // k [B][S][Z]
  unsigned short* vT  = (unsigned short*)take(4ULL * 1024 * 2048 * 2); // v^T [B][E][S]
  unsigned short* Pb  = (unsigned short*)take(4ULL * 2048 * 2048 * 2); // P~ [B][T][S]
  unsigned short* hrb = (unsigned short*)take(8192ULL * 1024 * 2); // h*r bf16
  float*          rs  = (float*)take(4ULL * 2048 * 4);             // rowsums [B][T]

  dim3 blk(256);
  dim3 gblk(512);
  // fused casts + rs memset (20737 blocks)
  cast_all<<<20737, blk, 0, stream>>>(query, key, Wq, Wk, Wv, Wh,
      qbf, kbr, Wqb, Wkb, Wvb, Whb, rs);

  // merged N=128 projections: z=0 q-slice (Wq rows 2048..2175), z=1 k-proj
  gemm_nz128<<<dim3(64, 1, 2), blk, 0, stream>>>(
      qbf, kbr, Wqb + 2048LL * 1024, Wkb,
      bq + 2048, bk, gamma, gamma + 128, beta, beta + 128, qpj, kpj);
  // g0 (control, unchanged): Wq main (cols 0..2047): u (sigmoid) + r (silu)
  gemm256<<<dim3(32, 8, 1), gblk, 0, stream>>>(qbf, 1024, Wqb, 1024, 1024,
      bq, (float*)ub, rbf);
  // g2: v^T[b][e][s] = silu(Wv @ kbr^T + bv)  (occupancy-freed R0, 512 blocks)
  gemm_bt<2><<<dim3(8, 64, 1), blk, 0, stream>>>(Wvb, 0, 1024, kbr, 0, 1024, 1024,
      bv, nullptr, vT, nullptr, nullptr);
  // g3: P~[b][t][s] = exp(scaling * q_b @ k_b^T), rowsums -> rs (1024 blocks)
  gemm_bt<3><<<dim3(16, 16, 4), blk, 0, stream>>>(qpj, 128, 512, kpj, 2048LL * 128, 128, 128,
      nullptr, rs, Pb, nullptr, nullptr);
  // g4: hr[t,b,e] = (P~_b @ vT_b^T)/rowsum * r  (512 blocks)
  gemm_bt<4><<<dim3(16, 8, 4), blk, 0, stream>>>(Pb, 2048LL * 2048, 2048,
      vT, 1024LL * 2048, 2048, 2048,
      nullptr, rs, hrb, rbf, nullptr);
  // g5: out = query + u * (tanh(hr @ Wh^T + bh) - query)  (512 blocks)
  gemm_bt<5><<<dim3(64, 8, 1), blk, 0, stream>>>(hrb, 0, 1024, Whb, 0, 1024, 1024,
      bh, out, nullptr, ub, query);
}

// Round 7
// 341.023 us; speedup vs baseline: 1.3862x; 1.3862x over previous
//
#include <hip/hip_runtime.h>
#include <cstdint>
#include <cstddef>

using short8  = __attribute__((ext_vector_type(8))) short;
using floatx4 = __attribute__((ext_vector_type(4))) float;

#define DEV __device__ __forceinline__

DEV float u2f(unsigned short u){
  union { unsigned int i; float f; } c; c.i = ((unsigned int)u) << 16; return c.f;
}
DEV unsigned short f2u(float f){
  union { float f; unsigned int i; } c; c.f = f;
  unsigned int i = c.i;
  i += 0x7fffu + ((i >> 16) & 1u);   // RNE to bf16 (finite values only here)
  return (unsigned short)(i >> 16);
}
DEV float sigmoidf_(float x){ return 1.0f / (1.0f + __expf(-x)); }
DEV float siluf_(float x){ return x / (1.0f + __expf(-x)); }

// async global->LDS, 16 B per lane; LDS dest must be wave-uniform base + lane*16
#define ASYNC_LD16(g, l) __builtin_amdgcn_global_load_lds( \
    (const __attribute__((address_space(1))) unsigned int*)(g), \
    (__attribute__((address_space(3))) unsigned int*)(l), 16, 0, 0)

#define MFMA_BF16 __builtin_amdgcn_mfma_f32_16x16x32_bf16

// raw barrier, opaque to the compiler's waitcnt-insertion pass: no implicit
// vmcnt(0) drain can be attached (R3-proven: 122us -> 53.8us on gemm256).
#define SBAR() asm volatile("s_barrier" ::: "memory")
#define LGKM0() asm volatile("s_waitcnt lgkmcnt(0)" ::: "memory")

// problem-fixed sizes: T=2048 S=2048 B=4 E=1024 Z=128
constexpr float SCALING = 0.088388347648318447f; // 128^-0.5

// ---------------------------------------------------------------- casts (R4-exact)
__global__ __launch_bounds__(256) void cast_act(
    const float* __restrict__ q, const float* __restrict__ k,
    unsigned short* __restrict__ qo, unsigned short* __restrict__ ko)
{
  const int bid = blockIdx.x;
  const int e = threadIdx.x * 4;
  const float* src; unsigned short* dst;
  if (bid < 8192) {
    src = q + (long long)bid * 1024;
    dst = qo + (long long)bid * 1024;
  } else {
    const int m = bid - 8192;
    const int s = m >> 2, b = m & 3;
    src = k + (long long)m * 1024;
    dst = ko + ((long long)b * 2048 + s) * 1024;
  }
  const float4 v = *(const float4*)(src + e);
  ushort4 o; o.x=f2u(v.x); o.y=f2u(v.y); o.z=f2u(v.z); o.w=f2u(v.w);
  *(ushort4*)(dst + e) = o;
}

__global__ __launch_bounds__(256) void cast_w(
    const float* __restrict__ Wq, const float* __restrict__ Wk,
    const float* __restrict__ Wv, const float* __restrict__ Wh,
    unsigned short* __restrict__ oq, unsigned short* __restrict__ ok,
    unsigned short* __restrict__ ov, unsigned short* __restrict__ oh)
{
  const int bid = blockIdx.x;
  const int e = threadIdx.x * 4;
  const float* src; unsigned short* dst;
  if (bid < 2176)      { src = Wq + (long long)bid * 1024;        dst = oq + (long long)bid * 1024; }
  else if (bid < 2304) { src = Wk + (long long)(bid-2176) * 1024; dst = ok + (long long)(bid-2176) * 1024; }
  else if (bid < 3328) { src = Wv + (long long)(bid-2304) * 1024; dst = ov + (long long)(bid-2304) * 1024; }
  else                 { src = Wh + (long long)(bid-3328) * 1024; dst = oh + (long long)(bid-3328) * 1024; }
  const float4 v = *(const float4*)(src + e);
  ushort4 o; o.x=f2u(v.x); o.y=f2u(v.y); o.z=f2u(v.z); o.w=f2u(v.w);
  *(ushort4*)(dst + e) = o;
}

// ---------------------------------------------------------------- merged N=128 GEMMs (R4-exact)
// z=0: qpj = silu(qbf @ WqSlice^T + bq[2048:])*gamma0+beta0   (q projection)
// z=1: kpj = silu(kbr @ Wk^T + bk)*gamma1+beta1                (k projection)
__global__ __launch_bounds__(256, 2)
void gemm_nz128(const unsigned short* __restrict__ A0, const unsigned short* __restrict__ A1,
                const unsigned short* __restrict__ B0, const unsigned short* __restrict__ B1,
                const float* __restrict__ bi0, const float* __restrict__ bi1,
                const float* __restrict__ g0,  const float* __restrict__ g1,
                const float* __restrict__ be0, const float* __restrict__ be1,
                unsigned short* __restrict__ o0, unsigned short* __restrict__ o1)
{
  __shared__ __align__(16) unsigned short As[128][64];
  __shared__ __align__(16) unsigned short Bs[128][64];

  const int tid = threadIdx.x;
  const int bm = blockIdx.x;
  const int z  = blockIdx.z;
  const unsigned short* Ag = z ? A1 : A0;
  const unsigned short* Bg = z ? B1 : B0;
  const float* bias = z ? bi1 : bi0;
  const float* gam  = z ? g1  : g0;
  const float* bet  = z ? be1 : be0;
  unsigned short* ob = z ? o1 : o0;
  const int row0 = bm * 128;

  const int lane = tid & 63;
  const int wv   = tid >> 6;
  const int wm   = (wv & 1) * 64;
  const int wn   = (wv >> 1) * 64;
  const int lr   = lane & 15;
  const int lq   = lane >> 4;
  const int r7   = lr & 7;

  const unsigned short* gA[4]; const unsigned short* gB[4];
  unsigned short* lA[4]; unsigned short* lB[4];
  #pragma unroll
  for (int i = 0; i < 4; i++) {
    const int c  = tid + i * 256;
    const int rr = c >> 3;
    const int gc = (c & 7) ^ (rr & 7);
    gA[i] = Ag + (long long)(row0 + rr) * 1024 + gc * 8;
    gB[i] = Bg + (long long)rr * 1024 + gc * 8;
    lA[i] = &As[0][0] + c * 8;
    lB[i] = &Bs[0][0] + c * 8;
  }

  floatx4 acc[4][4];
  const floatx4 zero = {0.f, 0.f, 0.f, 0.f};
  #pragma unroll
  for (int i = 0; i < 4; i++)
    #pragma unroll
    for (int j = 0; j < 4; j++) acc[i][j] = zero;

  for (int kt = 0; kt < 1024; kt += 64) {
    #pragma unroll
    for (int i = 0; i < 4; i++) {
      ASYNC_LD16(gA[i] + kt, lA[i]);
      ASYNC_LD16(gB[i] + kt, lB[i]);
    }
    __syncthreads();
    #pragma unroll
    for (int ks = 0; ks < 64; ks += 32) {
      const int k8 = ks >> 3;
      short8 af[4], bfv[4];
      #pragma unroll
      for (int i = 0; i < 4; i++) {
        const int sc = (lq + k8) ^ r7;
        af[i]  = *(const short8*)(&As[wm + i*16 + lr][sc * 8]);
        bfv[i] = *(const short8*)(&Bs[wn + i*16 + lr][sc * 8]);
      }
      #pragma unroll
      for (int mi = 0; mi < 4; mi++)
        #pragma unroll
        for (int ni = 0; ni < 4; ni++)
          acc[mi][ni] = MFMA_BF16(af[mi], bfv[ni], acc[mi][ni], 0, 0, 0);
    }
    __syncthreads();
  }

  #pragma unroll
  for (int mi = 0; mi < 4; mi++)
    #pragma unroll
    for (int ni = 0; ni < 4; ni++)
      #pragma unroll
      for (int r = 0; r < 4; r++) {
        const int gm = row0 + wm + mi * 16 + lq * 4 + r;
        const int gn = wn + ni * 16 + lr;
        float v = acc[mi][ni][r] + bias[gn];
        ob[(long long)gm * 128 + gn] = f2u(siluf_(v) * gam[gn] + bet[gn]);
      }
}

// ---------------------------------------------------------------- 256x256 counted-vmcnt GEMM (g0)
// R5-version (measured 51.2us). Raw SBAR + counted vmcnt(8), minimal fences.
__global__ __launch_bounds__(512, 2)
void gemm256(const unsigned short* __restrict__ A, int lda,
             const unsigned short* __restrict__ Bm, int ldb,
             int K,
             const float* __restrict__ bias,
             float* __restrict__ f0,
             unsigned short* __restrict__ b0)
{
  __shared__ __align__(16) unsigned short Ls[65536]; // 128 KiB

  const int tid = threadIdx.x;
  const int bm = blockIdx.x, bn = blockIdx.y;
  const int row0 = bm * 256;
  const int col0 = bn * 256;

  const int lane = tid & 63;
  const int wv   = tid >> 6;
  const int wr   = (wv >> 2) * 128;
  const int wc   = (wv & 3) * 64;
  const int lr   = lane & 15;
  const int lq   = lane >> 4;
  const int r7   = lr & 7;

  const int rr0 = tid >> 3;
  const int swz = ((tid & 7) ^ (rr0 & 7)) * 8;
  const unsigned short* gA0 = A  + (long long)(row0 + rr0) * lda + swz;
  const unsigned short* gB0 = Bm + (long long)(col0 + rr0) * ldb + swz;
  const long long sA64 = 64LL * lda, sB64 = 64LL * ldb;
  unsigned short* lA0 = &Ls[0]     + tid * 8;
  unsigned short* lB0 = &Ls[16384] + tid * 8;

  floatx4 acc[8][4];
  const floatx4 zero = {0.f, 0.f, 0.f, 0.f};
  #pragma unroll
  for (int i = 0; i < 8; i++)
    #pragma unroll
    for (int j = 0; j < 4; j++) acc[i][j] = zero;

  const int NT = K >> 6;

  #pragma unroll
  for (int i = 0; i < 4; i++) ASYNC_LD16(gA0 + i * sA64,      lA0 + i * 4096);
  #pragma unroll
  for (int i = 0; i < 4; i++) ASYNC_LD16(gB0 + i * sB64,      lB0 + i * 4096);
  #pragma unroll
  for (int i = 0; i < 4; i++) ASYNC_LD16(gA0 + i * sA64 + 64, lA0 + i * 4096 + 32768);
  #pragma unroll
  for (int i = 0; i < 4; i++) ASYNC_LD16(gB0 + i * sB64 + 64, lB0 + i * 4096 + 32768);
  asm volatile("s_waitcnt vmcnt(8)" ::: "memory");
  SBAR();

  for (int t = 0; t < NT; ++t) {
    const int cb = (t & 1) << 15;
    const unsigned short* Ab = &Ls[cb];
    const unsigned short* Bb = &Ls[cb + 16384];
    const bool st = (t + 2) < NT;
    const int kt2 = (t + 2) << 6;

    short8 afA[4][2], afB[4][2], bf01[2][2], bf23[2][2];

    // ---- ph1+ph2 (fused): 16 ds_reads; 32 MFMA Q(0-3, 0-3)
    #pragma unroll
    for (int mi = 0; mi < 4; mi++)
      #pragma unroll
      for (int k = 0; k < 2; k++)
        afA[mi][k] = *(const short8*)(Ab + (wr + mi*16 + lr) * 64 + (((k<<2) + lq) ^ r7) * 8);
    #pragma unroll
    for (int ni = 0; ni < 2; ni++)
      #pragma unroll
      for (int k = 0; k < 2; k++)
        bf01[ni][k] = *(const short8*)(Bb + (wc + ni*16 + lr) * 64 + (((k<<2) + lq) ^ r7) * 8);
    #pragma unroll
    for (int ni = 0; ni < 2; ni++)
      #pragma unroll
      for (int k = 0; k < 2; k++)
        bf23[ni][k] = *(const short8*)(Bb + (wc + (ni+2)*16 + lr) * 64 + (((k<<2) + lq) ^ r7) * 8);
    __builtin_amdgcn_s_setprio(1);
    #pragma unroll
    for (int mi = 0; mi < 4; mi++)
      #pragma unroll
      for (int ni = 0; ni < 2; ni++)
        #pragma unroll
        for (int k = 0; k < 2; k++)
          acc[mi][ni] = MFMA_BF16(afA[mi][k], bf01[ni][k], acc[mi][ni], 0, 0, 0);
    #pragma unroll
    for (int mi = 0; mi < 4; mi++)
      #pragma unroll
      for (int ni = 0; ni < 2; ni++)
        #pragma unroll
        for (int k = 0; k < 2; k++)
          acc[mi][ni+2] = MFMA_BF16(afA[mi][k], bf23[ni][k], acc[mi][ni+2], 0, 0, 0);
    __builtin_amdgcn_s_setprio(0);
    LGKM0();
    SBAR();

    // ---- ph3: 8 ds_reads (afB mi4-7); stage B(t+2); MFMA Q(4-7, 0-1)
    #pragma unroll
    for (int mi = 0; mi < 4; mi++)
      #pragma unroll
      for (int k = 0; k < 2; k++)
        afB[mi][k] = *(const short8*)(Ab + (wr + (mi+4)*16 + lr) * 64 + (((k<<2) + lq) ^ r7) * 8);
    if (st) {
      #pragma unroll
      for (int i = 0; i < 4; i++) ASYNC_LD16(gB0 + i * sB64 + kt2, lB0 + i * 4096 + cb);
    }
    __builtin_amdgcn_s_setprio(1);
    #pragma unroll
    for (int mi = 0; mi < 4; mi++)
      #pragma unroll
      for (int ni = 0; ni < 2; ni++)
        #pragma unroll
        for (int k = 0; k < 2; k++)
          acc[mi+4][ni] = MFMA_BF16(afB[mi][k], bf01[ni][k], acc[mi+4][ni], 0, 0, 0);
    __builtin_amdgcn_s_setprio(0);
    LGKM0();
    SBAR();

    // ---- ph4: stage A(t+2); MFMA Q(4-7, 2-3); boundary
    if (st) {
      #pragma unroll
      for (int i = 0; i < 4; i++) ASYNC_LD16(gA0 + i * sA64 + kt2, lA0 + i * 4096 + cb);
    }
    __builtin_amdgcn_s_setprio(1);
    #pragma unroll
    for (int mi = 0; mi < 4; mi++)
      #pragma unroll
      for (int ni = 0; ni < 2; ni++)
        #pragma unroll
        for (int k = 0; k < 2; k++)
          acc[mi+4][ni+2] = MFMA_BF16(afB[mi][k], bf23[ni][k], acc[mi+4][ni+2], 0, 0, 0);
    __builtin_amdgcn_s_setprio(0);
    if (st) { asm volatile("s_waitcnt vmcnt(8)" ::: "memory"); }
    else    { asm volatile("s_waitcnt vmcnt(0)" ::: "memory"); }
    SBAR();
  }

  // epilogue (N=2048: u for gn<1024 else r)
  #pragma unroll
  for (int mi = 0; mi < 8; mi++)
    #pragma unroll
    for (int ni = 0; ni < 4; ni++)
      #pragma unroll
      for (int r = 0; r < 4; r++) {
        const int gm = row0 + wr + mi * 16 + lq * 4 + r;
        const int gn = col0 + wc + ni * 16 + lr;
        float v = acc[mi][ni][r] + bias[gn];
        if (gn < 1024) {
          ((unsigned short*)f0)[(long long)gm * 1024 + gn] = f2u(sigmoidf_(v)); // u bf16
        } else {
          b0[(long long)gm * 1024 + (gn - 1024)] = f2u(siluf_(v));    // r
        }
      }
}

// ---------------------------------------------------------------- 256x128 counted-vmcnt GEMM (R4-exact)
// EPI: 2 = v proj swapped (gm=e, gn=(b,s)); 5 = final out = q + u*(tanh(.)-q)
template<int EPI>
__global__ __launch_bounds__(512, 2)
void gemm_n128(const unsigned short* __restrict__ A, long long bsA, int lda,
               const unsigned short* __restrict__ Bm, long long bsB, int ldb,
               int K,
               const float* __restrict__ bias,
               float* __restrict__ f0,
               unsigned short* __restrict__ b0,
               const unsigned short* __restrict__ rmul,
               const float* __restrict__ qin)
{
  __shared__ __align__(16) unsigned short Ls[49152]; // 96 KiB: {A0,B0,A1,B1}

  const int tid = threadIdx.x;
  const int bm = blockIdx.x, bn = blockIdx.y, bz = blockIdx.z;
  const unsigned short* Ag = A  + (long long)bz * bsA;
  const unsigned short* Bg = Bm + (long long)bz * bsB;
  const int row0 = bm * 256;
  const int col0 = bn * 128;

  const int lane = tid & 63;
  const int wv   = tid >> 6;
  const int wr   = (wv & 3) * 64;
  const int wc   = (wv >> 2) * 64;
  const int lr   = lane & 15;
  const int lq   = lane >> 4;
  const int r7   = lr & 7;

  const int rr0 = tid >> 3;
  const int swz = ((tid & 7) ^ (rr0 & 7)) * 8;
  const unsigned short* gA0 = Ag + (long long)(row0 + rr0) * lda + swz;
  const unsigned short* gB0 = Bg + (long long)(col0 + rr0) * ldb + swz;
  const long long sA64 = 64LL * lda, sB64 = 64LL * ldb;
  unsigned short* lA0 = &Ls[0]     + tid * 8;
  unsigned short* lB0 = &Ls[16384] + tid * 8;

  floatx4 acc[4][4];
  const floatx4 zero = {0.f, 0.f, 0.f, 0.f};
  #pragma unroll
  for (int i = 0; i < 4; i++)
    #pragma unroll
    for (int j = 0; j < 4; j++) acc[i][j] = zero;

  const int NT = K >> 6;

  #pragma unroll
  for (int i = 0; i < 4; i++) ASYNC_LD16(gA0 + i * sA64,      lA0 + i * 4096);
  #pragma unroll
  for (int i = 0; i < 2; i++) ASYNC_LD16(gB0 + i * sB64,      lB0 + i * 4096);
  #pragma unroll
  for (int i = 0; i < 4; i++) ASYNC_LD16(gA0 + i * sA64 + 64, lA0 + i * 4096 + 24576);
  #pragma unroll
  for (int i = 0; i < 2; i++) ASYNC_LD16(gB0 + i * sB64 + 64, lB0 + i * 4096 + 24576);
  asm volatile("s_waitcnt vmcnt(6)" ::: "memory");
  SBAR();

  for (int t = 0; t < NT; ++t) {
    const int cb = (t & 1) * 24576;
    const unsigned short* Ab = &Ls[cb];
    const unsigned short* Bb = &Ls[cb + 16384];
    const bool st = (t + 2) < NT;
    const int kt2 = (t + 2) << 6;

    short8 afA[4][2], bfv[4][2];

    // ---- phase 1: all 16 ds_reads; lgkm-gate; 16 MFMA (ni0-1)
    #pragma unroll
    for (int mi = 0; mi < 4; mi++)
      #pragma unroll
      for (int k = 0; k < 2; k++)
        afA[mi][k] = *(const short8*)(Ab + (wr + mi*16 + lr) * 64 + (((k<<2) + lq) ^ r7) * 8);
    #pragma unroll
    for (int ni = 0; ni < 4; ni++)
      #pragma unroll
      for (int k = 0; k < 2; k++)
        bfv[ni][k] = *(const short8*)(Bb + (wc + ni*16 + lr) * 64 + (((k<<2) + lq) ^ r7) * 8);
    LGKM0();
    __builtin_amdgcn_sched_barrier(0);
    __builtin_amdgcn_s_setprio(1);
    #pragma unroll
    for (int mi = 0; mi < 4; mi++)
      #pragma unroll
      for (int ni = 0; ni < 2; ni++)
        #pragma unroll
        for (int k = 0; k < 2; k++)
          acc[mi][ni] = MFMA_BF16(afA[mi][k], bfv[ni][k], acc[mi][ni], 0, 0, 0);
    __builtin_amdgcn_s_setprio(0);
    SBAR();   // all waves' reads of tile t complete -> buffer slots free

    // ---- phase 2: stage t+2 (same-parity buffer); 16 MFMA (ni2-3, regs)
    if (st) {
      #pragma unroll
      for (int i = 0; i < 4; i++) ASYNC_LD16(gA0 + i * sA64 + kt2, lA0 + i * 4096 + cb);
      #pragma unroll
      for (int i = 0; i < 2; i++) ASYNC_LD16(gB0 + i * sB64 + kt2, lB0 + i * 4096 + cb);
    }
    __builtin_amdgcn_s_setprio(1);
    #pragma unroll
    for (int mi = 0; mi < 4; mi++)
      #pragma unroll
      for (int ni = 0; ni < 2; ni++)
        #pragma unroll
        for (int k = 0; k < 2; k++)
          acc[mi][ni+2] = MFMA_BF16(afA[mi][k], bfv[ni+2][k], acc[mi][ni+2], 0, 0, 0);
    __builtin_amdgcn_s_setprio(0);
    if (st) { asm volatile("s_waitcnt vmcnt(6)" ::: "memory"); }
    else    { asm volatile("s_waitcnt vmcnt(0)" ::: "memory"); }
    SBAR();
  }

  #pragma unroll
  for (int mi = 0; mi < 4; mi++) {
    #pragma unroll
    for (int ni = 0; ni < 4; ni++) {
      #pragma unroll
      for (int r = 0; r < 4; r++) {
        const int gm = row0 + wr + mi * 16 + lq * 4 + r;
        const int gn = col0 + wc + ni * 16 + lr;
        float v = acc[mi][ni][r];
        if constexpr (EPI == 2) {
          v += bias[gm];                                               // bias by e-row
          const int b = gn >> 11, s = gn & 2047;
          b0[((long long)b * 1024 + gm) * 2048 + s] = f2u(siluf_(v));  // v^T coalesced
        } else { // EPI == 5
          const long long idx = (long long)gm * 1024 + gn;
          const float tv = tanhf(v + bias[gn]);
          const float qv = qin[idx];
          f0[idx] = qv + u2f(rmul[idx]) * (tv - qv);                   // final out
        }
      }
    }
  }
}

// ---------------------------------------------------------------- fused attention (replaces g3+g4)
// Per block: b=bz, 64 t-rows (t0=by*64), 512 e-cols (eh*512). Grid (2,32,4)=256.
// Loop s in 32 steps of 64:
//   S = q(64x128Z) @ k_tile^T(64x128Z)  [q in regs, k in dbuf LDS]
//   P = exp(S*scale) -> LDS (64x64 bf16, gemm_bt A-swizzle: slot=chunk^(row&7))
//   acc += P(64x64) @ vT_tile^T(512x64) [V single-buf LDS, gemm_bt B-swizzle]
//   rowsum via ones-MFMA on wave 0 only (acc_sum[mi] += P-frag x ones)
// Epilogue: h = acc/rowsum; out = h * r  (same indexing as old EPI4).
// Sync: per-wave counted vmcnt (own loads) + raw SBAR (all waves issue identical
// staging sequences, so own-vmcnt + barrier == tile complete; R3-proven pattern).
__global__ __launch_bounds__(512, 2)
void attn_fused(const unsigned short* __restrict__ qpj,  // (T,B,Z): elem t*512+b*128+z
                const unsigned short* __restrict__ kpj,  // [B][S][Z]
                const unsigned short* __restrict__ vT,   // [B][E][S]
                const unsigned short* __restrict__ rbf,  // (T*B, E)
                unsigned short* __restrict__ hrb)        // (T*B, E) = h*r
{
  __shared__ __align__(16) unsigned short Vs[32768];     // 512 e-rows x 64 s  (64 KB)
  __shared__ __align__(16) unsigned short Ks[2][8192];   // 64 s-rows x 128 Z dbuf (32 KB)
  __shared__ __align__(16) unsigned short Ps[4096];      // 64 t x 64 s        (8 KB)
  __shared__ float rsl[64];

  const int tid = threadIdx.x;
  const int eh = blockIdx.x, ty = blockIdx.y, bz = blockIdx.z;
  const int t0 = ty * 64;

  const int lane = tid & 63;
  const int wv   = tid >> 6;
  const int lr   = lane & 15;
  const int lq   = lane >> 4;
  const int mi_s = wv & 3;          // S-phase: this wave's t-row fragment
  const int niA  = (wv >> 2) * 2;   // S-phase: s-col fragments niA, niA+1

  const unsigned short* kb_g = kpj + (long long)bz * 2048 * 128;
  const unsigned short* vb_g = vT  + (long long)bz * 1024 * 2048;

  // q fragments held in registers for the whole kernel (K=Z=128 -> 4 k-steps)
  short8 afq[4];
  {
    const unsigned short* qrow = qpj + (long long)bz * 128
                               + (long long)(t0 + mi_s * 16 + lr) * 512;
    #pragma unroll
    for (int kd = 0; kd < 4; kd++)
      afq[kd] = *(const short8*)(qrow + (kd * 4 + lq) * 8);
  }

  // staging bases. V: 8 chunks/row (64 s-cols), 8 instrs. k: 16 chunks/row, 2 instrs.
  const int rrV = tid >> 3;
  const int gcV = ((tid & 7) ^ (rrV & 7)) * 8;
  const unsigned short* gV0 = vb_g + (long long)(eh * 512 + rrV) * 2048 + gcV;
  unsigned short* lV0 = Vs + tid * 8;
  const int rrK = tid >> 4;
  const int gcK = ((tid & 15) ^ (rrK & 15)) * 8;
  const unsigned short* gK0 = kb_g + (long long)rrK * 128 + gcK;
  unsigned short* lK0 = &Ks[0][0] + tid * 8;

  floatx4 acc[4][4];     // PV accumulator: 64 t x (wv*64 .. +64) e
  floatx4 accSum[4];     // wave 0 only: rowsums
  const floatx4 zero = {0.f, 0.f, 0.f, 0.f};
  #pragma unroll
  for (int i = 0; i < 4; i++) {
    accSum[i] = zero;
    #pragma unroll
    for (int j = 0; j < 4; j++) acc[i][j] = zero;
  }
  const short ob = (short)0x3F80;   // bf16 1.0
  const short8 ones = {ob, ob, ob, ob, ob, ob, ob, ob};

  // prologue: k(0) -> Ks[0]
  #pragma unroll
  for (int i = 0; i < 2; i++) ASYNC_LD16(gK0 + i * 4096, lK0 + i * 4096);

  for (int t = 0; t < 32; ++t) {
    const unsigned short* Kb = &Ks[t & 1][0];
    const bool st = (t + 1) < 32;

    // stage V(t) (V-LDS freed by prev post-PV barrier) and k(t+1)
    #pragma unroll
    for (int i = 0; i < 8; i++)
      ASYNC_LD16(gV0 + (long long)i * 131072 + t * 64, lV0 + i * 4096);
    if (st) {
      unsigned short* lKn = &Ks[(t + 1) & 1][0] + tid * 8;
      #pragma unroll
      for (int i = 0; i < 2; i++)
        ASYNC_LD16(gK0 + (long long)(t + 1) * 8192 + i * 4096, lKn + i * 4096);
    }
    // k(t) landed (own loads older than the 10/8 just issued) + all-waves sync
    if (st) { asm volatile("s_waitcnt vmcnt(10)" ::: "memory"); }
    else    { asm volatile("s_waitcnt vmcnt(8)"  ::: "memory"); }
    SBAR();

    // ---- S phase: this wave computes S fragments (mi_s, niA) and (mi_s, niA+1)
    floatx4 accS[2] = {zero, zero};
    short8 bfk[2][4];
    #pragma unroll
    for (int f = 0; f < 2; f++)
      #pragma unroll
      for (int kd = 0; kd < 4; kd++)
        bfk[f][kd] = *(const short8*)(Kb + ((niA + f) * 16 + lr) * 128
                                         + (((kd * 4 + lq) ^ lr) & 15) * 8);
    #pragma unroll
    for (int f = 0; f < 2; f++)
      #pragma unroll
      for (int kd = 0; kd < 4; kd++)
        accS[f] = MFMA_BF16(afq[kd], bfk[f][kd], accS[f], 0, 0, 0);
    // exp -> P LDS (A-layout with slot = chunk ^ (row&7))
    #pragma unroll
    for (int f = 0; f < 2; f++) {
      const int nif = niA + f;
      #pragma unroll
      for (int r = 0; r < 4; r++) {
        const float e = __expf(accS[f][r] * SCALING);
        const int trow = mi_s * 16 + lq * 4 + r;
        const int scol = nif * 16 + lr;
        const int slot = (scol >> 3) ^ (trow & 7);
        Ps[trow * 64 + slot * 8 + (lr & 7)] = f2u(e);
      }
    }
    LGKM0();                                   // P-writes + k-reads drained (own)
    if (st) { asm volatile("s_waitcnt vmcnt(2)" ::: "memory"); }   // own V(t) done
    else    { asm volatile("s_waitcnt vmcnt(0)" ::: "memory"); }
    SBAR();                                    // all: P complete + V complete

    // ---- PV phase: acc += P(64x64) @ V_slice^T ; K=64 -> 2 k-steps
    short8 afP[4][2], bfv[4][2];
    #pragma unroll
    for (int mi = 0; mi < 4; mi++)
      #pragma unroll
      for (int k8 = 0; k8 < 2; k8++)
        afP[mi][k8] = *(const short8*)(Ps + (mi * 16 + lr) * 64
                                          + ((k8 * 4 + lq) ^ (lr & 7)) * 8);
    #pragma unroll
    for (int ni = 0; ni < 4; ni++)
      #pragma unroll
      for (int k8 = 0; k8 < 2; k8++)
        bfv[ni][k8] = *(const short8*)(Vs + (wv * 64 + ni * 16 + lr) * 64
                                          + ((k8 * 4 + lq) ^ (lr & 7)) * 8);
    __builtin_amdgcn_s_setprio(1);
    #pragma unroll
    for (int mi = 0; mi < 4; mi++)
      #pragma unroll
      for (int ni = 0; ni < 4; ni++)
        #pragma unroll
        for (int k8 = 0; k8 < 2; k8++)
          acc[mi][ni] = MFMA_BF16(afP[mi][k8], bfv[ni][k8], acc[mi][ni], 0, 0, 0);
    __builtin_amdgcn_s_setprio(0);
    if (wv == 0) {    // rowsums: P x ones (cols all equal -> rowsum in each lane)
      #pragma unroll
      for (int mi = 0; mi < 4; mi++)
        #pragma unroll
        for (int k8 = 0; k8 < 2; k8++)
          accSum[mi] = MFMA_BF16(afP[mi][k8], ones, accSum[mi], 0, 0, 0);
    }
    LGKM0();                                   // P+V reads drained (own)
    SBAR();                                    // -> next step may overwrite V, P
  }

  // ---- epilogue: broadcast rowsums, normalize, apply r-gate
  if (wv == 0 && lr == 0) {
    #pragma unroll
    for (int mi = 0; mi < 4; mi++)
      #pragma unroll
      for (int r = 0; r < 4; r++)
        rsl[mi * 16 + lq * 4 + r] = accSum[mi][r];
  }
  LGKM0();
  SBAR();
  #pragma unroll
  for (int mi = 0; mi < 4; mi++) {
    float iv[4];
    #pragma unroll
    for (int r = 0; r < 4; r++) iv[r] = 1.0f / rsl[mi * 16 + lq * 4 + r];
    #pragma unroll
    for (int ni = 0; ni < 4; ni++) {
      #pragma unroll
      for (int r = 0; r < 4; r++) {
        const int gt = t0 + mi * 16 + lq * 4 + r;
        const int ge = eh * 512 + wv * 64 + ni * 16 + lr;
        const long long idx = ((long long)gt * 4 + bz) * 1024 + ge;
        hrb[idx] = f2u(acc[mi][ni][r] * iv[r] * u2f(rbf[idx]));
      }
    }
  }
}

// ---------------------------------------------------------------- launch
extern "C" void kernel_launch(void* const* d_in, const int* in_sizes, int n_in,
                              void* d_out, int out_size, void* d_ws, size_t ws_size,
                              hipStream_t stream)
{
  (void)in_sizes; (void)n_in; (void)out_size; (void)ws_size;
  const float* query = (const float*)d_in[0];
  const float* key   = (const float*)d_in[1];
  const float* Wq    = (const float*)d_in[2];
  const float* bq    = (const float*)d_in[3];
  const float* Wk    = (const float*)d_in[4];
  const float* bk    = (const float*)d_in[5];
  const float* Wv    = (const float*)d_in[6];
  const float* bv    = (const float*)d_in[7];
  const float* Wh    = (const float*)d_in[8];
  const float* bh    = (const float*)d_in[9];
  const float* gamma = (const float*)d_in[10];
  const float* beta  = (const float*)d_in[11];
  float* out = (float*)d_out;

  char* p = (char*)d_ws;
  auto take = [&](size_t bytes) -> char* {
    char* r = p; p += (bytes + 255) & ~(size_t)255; return r;
  };
  unsigned short* qbf = (unsigned short*)take(8192ULL * 1024 * 2); // query bf16 (T*B,E)
  unsigned short* kbr = (unsigned short*)take(8192ULL * 1024 * 2); // key bf16 [B][S][E]
  unsigned short* Wqb = (unsigned short*)take(2176ULL * 1024 * 2);
  unsigned short* Wkb = (unsigned short*)take(128ULL  * 1024 * 2);
  unsigned short* Wvb = (unsigned short*)take(1024ULL * 1024 * 2);
  unsigned short* Whb = (unsigned short*)take(1024ULL * 1024 * 2);
  unsigned short* ub  = (unsigned short*)take(8192ULL * 1024 * 2); // u gate bf16
  unsigned short* rbf = (unsigned short*)take(8192ULL * 1024 * 2); // r bf16
  unsigned short* qpj = (unsigned short*)take(8192ULL * 128 * 2);  // q (T,B,Z)
  unsigned short* kpj = (unsigned short*)take(8192ULL * 128 * 2);  // k [B][S][Z]
  unsigned short* vT  = (unsigned short*)take(4ULL * 1024 * 2048 * 2); // v^T [B][E][S]
  unsigned short* hrb = (unsigned short*)take(8192ULL * 1024 * 2); // h*r bf16

  dim3 blk(256);
  dim3 gblk(512);
  cast_act<<<16384, blk, 0, stream>>>(query, key, qbf, kbr);
  cast_w<<<4352, blk, 0, stream>>>(Wq, Wk, Wv, Wh, Wqb, Wkb, Wvb, Whb);

  // merged N=128 projections: z=0 q-slice (Wq rows 2048..2175), z=1 k-proj
  gemm_nz128<<<dim3(64, 1, 2), blk, 0, stream>>>(
      qbf, kbr, Wqb + 2048LL * 1024, Wkb,
      bq + 2048, bk, gamma, gamma + 128, beta, beta + 128, qpj, kpj);
  // g0: Wq main (cols 0..2047): u (sigmoid) + r (silu)
  gemm256<<<dim3(32, 8, 1), gblk, 0, stream>>>(qbf, 1024, Wqb, 1024, 1024,
      bq, (float*)ub, rbf);
  // g2: v^T[b][e][s] = silu(Wv @ kbr^T + bv)
  gemm_n128<2><<<dim3(4, 64, 1), gblk, 0, stream>>>(Wvb, 0, 1024, kbr, 0, 1024, 1024,
      bv, nullptr, vT, nullptr, nullptr);
  // fused g3+g4: hr = softmax(q k^T / sqrt(Z)) @ V * r  (no P materialization)
  attn_fused<<<dim3(2, 32, 4), gblk, 0, stream>>>(qpj, kpj, vT, rbf, hrb);
  // g5: out = query + u * (tanh(hr @ Wh^T + bh) - query)
  gemm_n128<5><<<dim3(32, 8, 1), gblk, 0, stream>>>(hrb, 0, 1024, Whb, 0, 1024, 1024,
      bh, out, nullptr, ub, query);
}

// Round 8
// 329.545 us; speedup vs baseline: 1.4345x; 1.0348x over previous
//
#include <hip/hip_runtime.h>
#include <cstdint>
#include <cstddef>

using short8  = __attribute__((ext_vector_type(8))) short;
using floatx4 = __attribute__((ext_vector_type(4))) float;

#define DEV __device__ __forceinline__

DEV float u2f(unsigned short u){
  union { unsigned int i; float f; } c; c.i = ((unsigned int)u) << 16; return c.f;
}
DEV unsigned short f2u(float f){
  union { float f; unsigned int i; } c; c.f = f;
  unsigned int i = c.i;
  i += 0x7fffu + ((i >> 16) & 1u);   // RNE to bf16 (finite values only here)
  return (unsigned short)(i >> 16);
}
DEV float sigmoidf_(float x){ return 1.0f / (1.0f + __expf(-x)); }
DEV float siluf_(float x){ return x / (1.0f + __expf(-x)); }

// async global->LDS, 16 B per lane; LDS dest must be wave-uniform base + lane*16
#define ASYNC_LD16(g, l) __builtin_amdgcn_global_load_lds( \
    (const __attribute__((address_space(1))) unsigned int*)(g), \
    (__attribute__((address_space(3))) unsigned int*)(l), 16, 0, 0)

#define MFMA_BF16 __builtin_amdgcn_mfma_f32_16x16x32_bf16

// raw barrier, opaque to the compiler's waitcnt-insertion pass: no implicit
// vmcnt(0) drain can be attached (R3-proven: 122us -> 53.8us on gemm256).
#define SBAR() asm volatile("s_barrier" ::: "memory")
#define LGKM0() asm volatile("s_waitcnt lgkmcnt(0)" ::: "memory")

// problem-fixed sizes: T=2048 S=2048 B=4 E=1024 Z=128
constexpr float SCALING = 0.088388347648318447f; // 128^-0.5

// ---------------------------------------------------------------- fused casts
// [0,8192): query rows -> qbf; [8192,16384): key -> kbr (batch de-interleave)
// [16384,18560): Wq; [18560,18688): Wk; [18688,19712): Wv; [19712,20736): Wh
__global__ __launch_bounds__(256) void cast_all(
    const float* __restrict__ q, const float* __restrict__ k,
    const float* __restrict__ Wq, const float* __restrict__ Wk,
    const float* __restrict__ Wv, const float* __restrict__ Wh,
    unsigned short* __restrict__ qo, unsigned short* __restrict__ ko,
    unsigned short* __restrict__ oq, unsigned short* __restrict__ ok,
    unsigned short* __restrict__ ov, unsigned short* __restrict__ oh)
{
  const int bid = blockIdx.x;
  const int e = threadIdx.x * 4;
  const float* src; unsigned short* dst;
  if (bid < 8192) {
    src = q + (long long)bid * 1024;
    dst = qo + (long long)bid * 1024;
  } else if (bid < 16384) {
    const int m = bid - 8192;
    const int s = m >> 2, b = m & 3;
    src = k + (long long)m * 1024;
    dst = ko + ((long long)b * 2048 + s) * 1024;
  } else if (bid < 18560) { src = Wq + (long long)(bid-16384) * 1024; dst = oq + (long long)(bid-16384) * 1024; }
  else if (bid < 18688)   { src = Wk + (long long)(bid-18560) * 1024; dst = ok + (long long)(bid-18560) * 1024; }
  else if (bid < 19712)   { src = Wv + (long long)(bid-18688) * 1024; dst = ov + (long long)(bid-18688) * 1024; }
  else                    { src = Wh + (long long)(bid-19712) * 1024; dst = oh + (long long)(bid-19712) * 1024; }
  const float4 v = *(const float4*)(src + e);
  ushort4 o; o.x=f2u(v.x); o.y=f2u(v.y); o.z=f2u(v.z); o.w=f2u(v.w);
  *(ushort4*)(dst + e) = o;
}

// ---------------------------------------------------------------- MEGA dispatch
// 576 blocks x 512 thr, one 128K LDS pool (all paths were 1 block/CU anyway).
// bid <256 : g0  = gemm256 body (R5-proven, 51.2us): Wq-main -> u, r
// bid <512 : g2  = gemm_n128<2> body (R4-proven): vT = silu(Wv @ kbr^T + bv)
// bid <576 : proj = same 2-phase 256x128 body, EPI1 epilogue:
//            z=0 q-slice (Wq rows 2048..2175) -> qpj ; z=1 k-proj -> kpj
// Heavy blocks first: light proj blocks tail-fill CUs as g0 blocks retire.
__global__ __launch_bounds__(512, 2)
void mega(const unsigned short* __restrict__ qbf,
          const unsigned short* __restrict__ Wqb,
          const unsigned short* __restrict__ kbr,
          const unsigned short* __restrict__ Wvb,
          const unsigned short* __restrict__ Wkb,
          const float* __restrict__ bq, const float* __restrict__ bk,
          const float* __restrict__ bv,
          const float* __restrict__ gamma, const float* __restrict__ beta,
          float* __restrict__ ub_f,          // u gate (bf16 via reinterpret)
          unsigned short* __restrict__ rbf,  // r
          unsigned short* __restrict__ vT,   // [B][E][S]
          unsigned short* __restrict__ qpj,  // (T,B,Z)
          unsigned short* __restrict__ kpj)  // [B][S][Z]
{
  __shared__ __align__(16) unsigned short Ls[65536]; // 128 KiB

  const int bid = blockIdx.x;
  const int tid = threadIdx.x;
  const int lane = tid & 63;
  const int wv   = tid >> 6;
  const int lr   = lane & 15;
  const int lq   = lane >> 4;
  const int r7   = lr & 7;

  const floatx4 zero = {0.f, 0.f, 0.f, 0.f};

  if (bid < 256) {
    // ================= g0: 256x256 counted-vmcnt GEMM (R5-exact body) =================
    const int bm = bid & 31, bn = bid >> 5;
    const int row0 = bm * 256;
    const int col0 = bn * 256;
    const int lda = 1024, ldb = 1024;
    const int wr = (wv >> 2) * 128;
    const int wc = (wv & 3) * 64;

    const int rr0 = tid >> 3;
    const int swz = ((tid & 7) ^ (rr0 & 7)) * 8;
    const unsigned short* gA0 = qbf + (long long)(row0 + rr0) * lda + swz;
    const unsigned short* gB0 = Wqb + (long long)(col0 + rr0) * ldb + swz;
    const long long sA64 = 64LL * lda, sB64 = 64LL * ldb;
    unsigned short* lA0 = &Ls[0]     + tid * 8;
    unsigned short* lB0 = &Ls[16384] + tid * 8;

    floatx4 acc[8][4];
    #pragma unroll
    for (int i = 0; i < 8; i++)
      #pragma unroll
      for (int j = 0; j < 4; j++) acc[i][j] = zero;

    const int NT = 16; // K=1024

    #pragma unroll
    for (int i = 0; i < 4; i++) ASYNC_LD16(gA0 + i * sA64,      lA0 + i * 4096);
    #pragma unroll
    for (int i = 0; i < 4; i++) ASYNC_LD16(gB0 + i * sB64,      lB0 + i * 4096);
    #pragma unroll
    for (int i = 0; i < 4; i++) ASYNC_LD16(gA0 + i * sA64 + 64, lA0 + i * 4096 + 32768);
    #pragma unroll
    for (int i = 0; i < 4; i++) ASYNC_LD16(gB0 + i * sB64 + 64, lB0 + i * 4096 + 32768);
    asm volatile("s_waitcnt vmcnt(8)" ::: "memory");
    SBAR();

    for (int t = 0; t < NT; ++t) {
      const int cb = (t & 1) << 15;
      const unsigned short* Ab = &Ls[cb];
      const unsigned short* Bb = &Ls[cb + 16384];
      const bool st = (t + 2) < NT;
      const int kt2 = (t + 2) << 6;

      short8 afA[4][2], afB[4][2], bf01[2][2], bf23[2][2];

      // ---- ph1+ph2 (fused): 16 ds_reads; 32 MFMA Q(0-3, 0-3)
      #pragma unroll
      for (int mi = 0; mi < 4; mi++)
        #pragma unroll
        for (int kk = 0; kk < 2; kk++)
          afA[mi][kk] = *(const short8*)(Ab + (wr + mi*16 + lr) * 64 + (((kk<<2) + lq) ^ r7) * 8);
      #pragma unroll
      for (int ni = 0; ni < 2; ni++)
        #pragma unroll
        for (int kk = 0; kk < 2; kk++)
          bf01[ni][kk] = *(const short8*)(Bb + (wc + ni*16 + lr) * 64 + (((kk<<2) + lq) ^ r7) * 8);
      #pragma unroll
      for (int ni = 0; ni < 2; ni++)
        #pragma unroll
        for (int kk = 0; kk < 2; kk++)
          bf23[ni][kk] = *(const short8*)(Bb + (wc + (ni+2)*16 + lr) * 64 + (((kk<<2) + lq) ^ r7) * 8);
      __builtin_amdgcn_s_setprio(1);
      #pragma unroll
      for (int mi = 0; mi < 4; mi++)
        #pragma unroll
        for (int ni = 0; ni < 2; ni++)
          #pragma unroll
          for (int kk = 0; kk < 2; kk++)
            acc[mi][ni] = MFMA_BF16(afA[mi][kk], bf01[ni][kk], acc[mi][ni], 0, 0, 0);
      #pragma unroll
      for (int mi = 0; mi < 4; mi++)
        #pragma unroll
        for (int ni = 0; ni < 2; ni++)
          #pragma unroll
          for (int kk = 0; kk < 2; kk++)
            acc[mi][ni+2] = MFMA_BF16(afA[mi][kk], bf23[ni][kk], acc[mi][ni+2], 0, 0, 0);
      __builtin_amdgcn_s_setprio(0);
      LGKM0();
      SBAR();

      // ---- ph3: 8 ds_reads (afB); stage B(t+2); MFMA Q(4-7, 0-1)
      #pragma unroll
      for (int mi = 0; mi < 4; mi++)
        #pragma unroll
        for (int kk = 0; kk < 2; kk++)
          afB[mi][kk] = *(const short8*)(Ab + (wr + (mi+4)*16 + lr) * 64 + (((kk<<2) + lq) ^ r7) * 8);
      if (st) {
        #pragma unroll
        for (int i = 0; i < 4; i++) ASYNC_LD16(gB0 + i * sB64 + kt2, lB0 + i * 4096 + cb);
      }
      __builtin_amdgcn_s_setprio(1);
      #pragma unroll
      for (int mi = 0; mi < 4; mi++)
        #pragma unroll
        for (int ni = 0; ni < 2; ni++)
          #pragma unroll
          for (int kk = 0; kk < 2; kk++)
            acc[mi+4][ni] = MFMA_BF16(afB[mi][kk], bf01[ni][kk], acc[mi+4][ni], 0, 0, 0);
      __builtin_amdgcn_s_setprio(0);
      LGKM0();
      SBAR();

      // ---- ph4: stage A(t+2); MFMA Q(4-7, 2-3); boundary
      if (st) {
        #pragma unroll
        for (int i = 0; i < 4; i++) ASYNC_LD16(gA0 + i * sA64 + kt2, lA0 + i * 4096 + cb);
      }
      __builtin_amdgcn_s_setprio(1);
      #pragma unroll
      for (int mi = 0; mi < 4; mi++)
        #pragma unroll
        for (int ni = 0; ni < 2; ni++)
          #pragma unroll
          for (int kk = 0; kk < 2; kk++)
            acc[mi+4][ni+2] = MFMA_BF16(afB[mi][kk], bf23[ni][kk], acc[mi+4][ni+2], 0, 0, 0);
      __builtin_amdgcn_s_setprio(0);
      if (st) { asm volatile("s_waitcnt vmcnt(8)" ::: "memory"); }
      else    { asm volatile("s_waitcnt vmcnt(0)" ::: "memory"); }
      SBAR();
    }

    // epilogue: u (sigmoid, bf16) for gn<1024 else r (silu)
    #pragma unroll
    for (int mi = 0; mi < 8; mi++)
      #pragma unroll
      for (int ni = 0; ni < 4; ni++)
        #pragma unroll
        for (int r = 0; r < 4; r++) {
          const int gm = row0 + wr + mi * 16 + lq * 4 + r;
          const int gn = col0 + wc + ni * 16 + lr;
          float v = acc[mi][ni][r] + bq[gn];
          if (gn < 1024) {
            ((unsigned short*)ub_f)[(long long)gm * 1024 + gn] = f2u(sigmoidf_(v));
          } else {
            rbf[(long long)gm * 1024 + (gn - 1024)] = f2u(siluf_(v));
          }
        }
  } else {
    // ================= 256x128 2-phase counted-vmcnt body (R4-exact) =================
    // decode: g2 (256 blocks) or proj (64 blocks: z=0 q-slice, z=1 k-proj)
    const unsigned short* Ag; const unsigned short* Bg;
    int row0, col0, zproj = -1;
    if (bid < 512) {
      const int idx = bid - 256;          // g2: grid (4,64)
      row0 = (idx & 3) * 256;             // e-rows of Wv
      col0 = (idx >> 2) * 128;            // (b,s) cols
      Ag = Wvb; Bg = kbr;
    } else {
      const int idx = bid - 512;          // proj: 64 blocks
      zproj = idx >> 5;                   // 0: q-slice, 1: k-proj
      row0 = (idx & 31) * 256;            // M=8192
      col0 = 0;                           // N=128
      Ag = zproj ? kbr : qbf;
      Bg = zproj ? Wkb : (Wqb + 2048LL * 1024);
    }
    const int lda = 1024, ldb = 1024;
    const int wr = (wv & 3) * 64;
    const int wc = (wv >> 2) * 64;

    const int rr0 = tid >> 3;
    const int swz = ((tid & 7) ^ (rr0 & 7)) * 8;
    const unsigned short* gA0 = Ag + (long long)(row0 + rr0) * lda + swz;
    const unsigned short* gB0 = Bg + (long long)(col0 + rr0) * ldb + swz;
    const long long sA64 = 64LL * lda, sB64 = 64LL * ldb;
    unsigned short* lA0 = &Ls[0]     + tid * 8;
    unsigned short* lB0 = &Ls[16384] + tid * 8;

    floatx4 acc[4][4];
    #pragma unroll
    for (int i = 0; i < 4; i++)
      #pragma unroll
      for (int j = 0; j < 4; j++) acc[i][j] = zero;

    const int NT = 16; // K=1024

    #pragma unroll
    for (int i = 0; i < 4; i++) ASYNC_LD16(gA0 + i * sA64,      lA0 + i * 4096);
    #pragma unroll
    for (int i = 0; i < 2; i++) ASYNC_LD16(gB0 + i * sB64,      lB0 + i * 4096);
    #pragma unroll
    for (int i = 0; i < 4; i++) ASYNC_LD16(gA0 + i * sA64 + 64, lA0 + i * 4096 + 24576);
    #pragma unroll
    for (int i = 0; i < 2; i++) ASYNC_LD16(gB0 + i * sB64 + 64, lB0 + i * 4096 + 24576);
    asm volatile("s_waitcnt vmcnt(6)" ::: "memory");
    SBAR();

    for (int t = 0; t < NT; ++t) {
      const int cb = (t & 1) * 24576;
      const unsigned short* Ab = &Ls[cb];
      const unsigned short* Bb = &Ls[cb + 16384];
      const bool st = (t + 2) < NT;
      const int kt2 = (t + 2) << 6;

      short8 afA[4][2], bfv[4][2];

      // ---- phase 1: all 16 ds_reads; lgkm-gate; 16 MFMA (ni0-1)
      #pragma unroll
      for (int mi = 0; mi < 4; mi++)
        #pragma unroll
        for (int kk = 0; kk < 2; kk++)
          afA[mi][kk] = *(const short8*)(Ab + (wr + mi*16 + lr) * 64 + (((kk<<2) + lq) ^ r7) * 8);
      #pragma unroll
      for (int ni = 0; ni < 4; ni++)
        #pragma unroll
        for (int kk = 0; kk < 2; kk++)
          bfv[ni][kk] = *(const short8*)(Bb + (wc + ni*16 + lr) * 64 + (((kk<<2) + lq) ^ r7) * 8);
      LGKM0();
      __builtin_amdgcn_sched_barrier(0);
      __builtin_amdgcn_s_setprio(1);
      #pragma unroll
      for (int mi = 0; mi < 4; mi++)
        #pragma unroll
        for (int ni = 0; ni < 2; ni++)
          #pragma unroll
          for (int kk = 0; kk < 2; kk++)
            acc[mi][ni] = MFMA_BF16(afA[mi][kk], bfv[ni][kk], acc[mi][ni], 0, 0, 0);
      __builtin_amdgcn_s_setprio(0);
      SBAR();   // all waves' reads of tile t complete -> buffer slots free

      // ---- phase 2: stage t+2 (same-parity buffer); 16 MFMA (ni2-3, regs)
      if (st) {
        #pragma unroll
        for (int i = 0; i < 4; i++) ASYNC_LD16(gA0 + i * sA64 + kt2, lA0 + i * 4096 + cb);
        #pragma unroll
        for (int i = 0; i < 2; i++) ASYNC_LD16(gB0 + i * sB64 + kt2, lB0 + i * 4096 + cb);
      }
      __builtin_amdgcn_s_setprio(1);
      #pragma unroll
      for (int mi = 0; mi < 4; mi++)
        #pragma unroll
        for (int ni = 0; ni < 2; ni++)
          #pragma unroll
          for (int kk = 0; kk < 2; kk++)
            acc[mi][ni+2] = MFMA_BF16(afA[mi][kk], bfv[ni+2][kk], acc[mi][ni+2], 0, 0, 0);
      __builtin_amdgcn_s_setprio(0);
      if (st) { asm volatile("s_waitcnt vmcnt(6)" ::: "memory"); }
      else    { asm volatile("s_waitcnt vmcnt(0)" ::: "memory"); }
      SBAR();
    }

    // epilogues
    if (zproj < 0) {
      // g2: vT[b][e][s] = silu(v + bv[e]), coalesced along s
      #pragma unroll
      for (int mi = 0; mi < 4; mi++)
        #pragma unroll
        for (int ni = 0; ni < 4; ni++)
          #pragma unroll
          for (int r = 0; r < 4; r++) {
            const int gm = row0 + wr + mi * 16 + lq * 4 + r;
            const int gn = col0 + wc + ni * 16 + lr;
            const float v = acc[mi][ni][r] + bv[gm];
            const int b = gn >> 11, s = gn & 2047;
            vT[((long long)b * 1024 + gm) * 2048 + s] = f2u(siluf_(v));
          }
    } else {
      const float* bias = zproj ? bk : (bq + 2048);
      const float* gam  = zproj ? (gamma + 128) : gamma;
      const float* bet  = zproj ? (beta + 128)  : beta;
      unsigned short* ob = zproj ? kpj : qpj;
      #pragma unroll
      for (int mi = 0; mi < 4; mi++)
        #pragma unroll
        for (int ni = 0; ni < 4; ni++)
          #pragma unroll
          for (int r = 0; r < 4; r++) {
            const int gm = row0 + wr + mi * 16 + lq * 4 + r;
            const int gn = wc + ni * 16 + lr;
            const float v = acc[mi][ni][r] + bias[gn];
            ob[(long long)gm * 128 + gn] = f2u(siluf_(v) * gam[gn] + bet[gn]);
          }
    }
  }
}

// ---------------------------------------------------------------- 256x128 counted-vmcnt GEMM (g5, R4-exact)
__global__ __launch_bounds__(512, 2)
void gemm_g5(const unsigned short* __restrict__ A, int lda,
             const unsigned short* __restrict__ Bm, int ldb,
             int K,
             const float* __restrict__ bias,
             float* __restrict__ f0,
             const unsigned short* __restrict__ rmul,
             const float* __restrict__ qin)
{
  __shared__ __align__(16) unsigned short Ls[49152]; // 96 KiB

  const int tid = threadIdx.x;
  const int bm = blockIdx.x, bn = blockIdx.y;
  const int row0 = bm * 256;
  const int col0 = bn * 128;

  const int lane = tid & 63;
  const int wv   = tid >> 6;
  const int wr   = (wv & 3) * 64;
  const int wc   = (wv >> 2) * 64;
  const int lr   = lane & 15;
  const int lq   = lane >> 4;
  const int r7   = lr & 7;

  const int rr0 = tid >> 3;
  const int swz = ((tid & 7) ^ (rr0 & 7)) * 8;
  const unsigned short* gA0 = A  + (long long)(row0 + rr0) * lda + swz;
  const unsigned short* gB0 = Bm + (long long)(col0 + rr0) * ldb + swz;
  const long long sA64 = 64LL * lda, sB64 = 64LL * ldb;
  unsigned short* lA0 = &Ls[0]     + tid * 8;
  unsigned short* lB0 = &Ls[16384] + tid * 8;

  floatx4 acc[4][4];
  const floatx4 zero = {0.f, 0.f, 0.f, 0.f};
  #pragma unroll
  for (int i = 0; i < 4; i++)
    #pragma unroll
    for (int j = 0; j < 4; j++) acc[i][j] = zero;

  const int NT = K >> 6;

  #pragma unroll
  for (int i = 0; i < 4; i++) ASYNC_LD16(gA0 + i * sA64,      lA0 + i * 4096);
  #pragma unroll
  for (int i = 0; i < 2; i++) ASYNC_LD16(gB0 + i * sB64,      lB0 + i * 4096);
  #pragma unroll
  for (int i = 0; i < 4; i++) ASYNC_LD16(gA0 + i * sA64 + 64, lA0 + i * 4096 + 24576);
  #pragma unroll
  for (int i = 0; i < 2; i++) ASYNC_LD16(gB0 + i * sB64 + 64, lB0 + i * 4096 + 24576);
  asm volatile("s_waitcnt vmcnt(6)" ::: "memory");
  SBAR();

  for (int t = 0; t < NT; ++t) {
    const int cb = (t & 1) * 24576;
    const unsigned short* Ab = &Ls[cb];
    const unsigned short* Bb = &Ls[cb + 16384];
    const bool st = (t + 2) < NT;
    const int kt2 = (t + 2) << 6;

    short8 afA[4][2], bfv[4][2];

    #pragma unroll
    for (int mi = 0; mi < 4; mi++)
      #pragma unroll
      for (int kk = 0; kk < 2; kk++)
        afA[mi][kk] = *(const short8*)(Ab + (wr + mi*16 + lr) * 64 + (((kk<<2) + lq) ^ r7) * 8);
    #pragma unroll
    for (int ni = 0; ni < 4; ni++)
      #pragma unroll
      for (int kk = 0; kk < 2; kk++)
        bfv[ni][kk] = *(const short8*)(Bb + (wc + ni*16 + lr) * 64 + (((kk<<2) + lq) ^ r7) * 8);
    LGKM0();
    __builtin_amdgcn_sched_barrier(0);
    __builtin_amdgcn_s_setprio(1);
    #pragma unroll
    for (int mi = 0; mi < 4; mi++)
      #pragma unroll
      for (int ni = 0; ni < 2; ni++)
        #pragma unroll
        for (int kk = 0; kk < 2; kk++)
          acc[mi][ni] = MFMA_BF16(afA[mi][kk], bfv[ni][kk], acc[mi][ni], 0, 0, 0);
    __builtin_amdgcn_s_setprio(0);
    SBAR();

    if (st) {
      #pragma unroll
      for (int i = 0; i < 4; i++) ASYNC_LD16(gA0 + i * sA64 + kt2, lA0 + i * 4096 + cb);
      #pragma unroll
      for (int i = 0; i < 2; i++) ASYNC_LD16(gB0 + i * sB64 + kt2, lB0 + i * 4096 + cb);
    }
    __builtin_amdgcn_s_setprio(1);
    #pragma unroll
    for (int mi = 0; mi < 4; mi++)
      #pragma unroll
      for (int ni = 0; ni < 2; ni++)
        #pragma unroll
        for (int kk = 0; kk < 2; kk++)
          acc[mi][ni+2] = MFMA_BF16(afA[mi][kk], bfv[ni+2][kk], acc[mi][ni+2], 0, 0, 0);
    __builtin_amdgcn_s_setprio(0);
    if (st) { asm volatile("s_waitcnt vmcnt(6)" ::: "memory"); }
    else    { asm volatile("s_waitcnt vmcnt(0)" ::: "memory"); }
    SBAR();
  }

  #pragma unroll
  for (int mi = 0; mi < 4; mi++)
    #pragma unroll
    for (int ni = 0; ni < 4; ni++)
      #pragma unroll
      for (int r = 0; r < 4; r++) {
        const int gm = row0 + wr + mi * 16 + lq * 4 + r;
        const int gn = col0 + wc + ni * 16 + lr;
        const long long idx = (long long)gm * 1024 + gn;
        const float tv = tanhf(acc[mi][ni][r] + bias[gn]);
        const float qv = qin[idx];
        f0[idx] = qv + u2f(rmul[idx]) * (tv - qv);
      }
}

// ---------------------------------------------------------------- fused attention (R7-exact, 75us measured)
__global__ __launch_bounds__(512, 2)
void attn_fused(const unsigned short* __restrict__ qpj,  // (T,B,Z)
                const unsigned short* __restrict__ kpj,  // [B][S][Z]
                const unsigned short* __restrict__ vT,   // [B][E][S]
                const unsigned short* __restrict__ rbf,  // (T*B, E)
                unsigned short* __restrict__ hrb)        // (T*B, E) = h*r
{
  __shared__ __align__(16) unsigned short Vs[32768];     // 512 e-rows x 64 s
  __shared__ __align__(16) unsigned short Ks[2][8192];   // 64 s-rows x 128 Z dbuf
  __shared__ __align__(16) unsigned short Ps[4096];      // 64 t x 64 s
  __shared__ float rsl[64];

  const int tid = threadIdx.x;
  const int eh = blockIdx.x, ty = blockIdx.y, bz = blockIdx.z;
  const int t0 = ty * 64;

  const int lane = tid & 63;
  const int wv   = tid >> 6;
  const int lr   = lane & 15;
  const int lq   = lane >> 4;
  const int mi_s = wv & 3;
  const int niA  = (wv >> 2) * 2;

  const unsigned short* kb_g = kpj + (long long)bz * 2048 * 128;
  const unsigned short* vb_g = vT  + (long long)bz * 1024 * 2048;

  short8 afq[4];
  {
    const unsigned short* qrow = qpj + (long long)bz * 128
                               + (long long)(t0 + mi_s * 16 + lr) * 512;
    #pragma unroll
    for (int kd = 0; kd < 4; kd++)
      afq[kd] = *(const short8*)(qrow + (kd * 4 + lq) * 8);
  }

  const int rrV = tid >> 3;
  const int gcV = ((tid & 7) ^ (rrV & 7)) * 8;
  const unsigned short* gV0 = vb_g + (long long)(eh * 512 + rrV) * 2048 + gcV;
  unsigned short* lV0 = Vs + tid * 8;
  const int rrK = tid >> 4;
  const int gcK = ((tid & 15) ^ (rrK & 15)) * 8;
  const unsigned short* gK0 = kb_g + (long long)rrK * 128 + gcK;
  unsigned short* lK0 = &Ks[0][0] + tid * 8;

  floatx4 acc[4][4];
  floatx4 accSum[4];
  const floatx4 zero = {0.f, 0.f, 0.f, 0.f};
  #pragma unroll
  for (int i = 0; i < 4; i++) {
    accSum[i] = zero;
    #pragma unroll
    for (int j = 0; j < 4; j++) acc[i][j] = zero;
  }
  const short ob = (short)0x3F80;
  const short8 ones = {ob, ob, ob, ob, ob, ob, ob, ob};

  #pragma unroll
  for (int i = 0; i < 2; i++) ASYNC_LD16(gK0 + i * 4096, lK0 + i * 4096);

  for (int t = 0; t < 32; ++t) {
    const unsigned short* Kb = &Ks[t & 1][0];
    const bool st = (t + 1) < 32;

    #pragma unroll
    for (int i = 0; i < 8; i++)
      ASYNC_LD16(gV0 + (long long)i * 131072 + t * 64, lV0 + i * 4096);
    if (st) {
      unsigned short* lKn = &Ks[(t + 1) & 1][0] + tid * 8;
      #pragma unroll
      for (int i = 0; i < 2; i++)
        ASYNC_LD16(gK0 + (long long)(t + 1) * 8192 + i * 4096, lKn + i * 4096);
    }
    if (st) { asm volatile("s_waitcnt vmcnt(10)" ::: "memory"); }
    else    { asm volatile("s_waitcnt vmcnt(8)"  ::: "memory"); }
    SBAR();

    floatx4 accS[2] = {zero, zero};
    short8 bfk[2][4];
    #pragma unroll
    for (int f = 0; f < 2; f++)
      #pragma unroll
      for (int kd = 0; kd < 4; kd++)
        bfk[f][kd] = *(const short8*)(Kb + ((niA + f) * 16 + lr) * 128
                                         + (((kd * 4 + lq) ^ lr) & 15) * 8);
    #pragma unroll
    for (int f = 0; f < 2; f++)
      #pragma unroll
      for (int kd = 0; kd < 4; kd++)
        accS[f] = MFMA_BF16(afq[kd], bfk[f][kd], accS[f], 0, 0, 0);
    #pragma unroll
    for (int f = 0; f < 2; f++) {
      const int nif = niA + f;
      #pragma unroll
      for (int r = 0; r < 4; r++) {
        const float e = __expf(accS[f][r] * SCALING);
        const int trow = mi_s * 16 + lq * 4 + r;
        const int scol = nif * 16 + lr;
        const int slot = (scol >> 3) ^ (trow & 7);
        Ps[trow * 64 + slot * 8 + (lr & 7)] = f2u(e);
      }
    }
    LGKM0();
    if (st) { asm volatile("s_waitcnt vmcnt(2)" ::: "memory"); }
    else    { asm volatile("s_waitcnt vmcnt(0)" ::: "memory"); }
    SBAR();

    short8 afP[4][2], bfv[4][2];
    #pragma unroll
    for (int mi = 0; mi < 4; mi++)
      #pragma unroll
      for (int k8 = 0; k8 < 2; k8++)
        afP[mi][k8] = *(const short8*)(Ps + (mi * 16 + lr) * 64
                                          + ((k8 * 4 + lq) ^ (lr & 7)) * 8);
    #pragma unroll
    for (int ni = 0; ni < 4; ni++)
      #pragma unroll
      for (int k8 = 0; k8 < 2; k8++)
        bfv[ni][k8] = *(const short8*)(Vs + (wv * 64 + ni * 16 + lr) * 64
                                          + ((k8 * 4 + lq) ^ (lr & 7)) * 8);
    __builtin_amdgcn_s_setprio(1);
    #pragma unroll
    for (int mi = 0; mi < 4; mi++)
      #pragma unroll
      for (int ni = 0; ni < 4; ni++)
        #pragma unroll
        for (int k8 = 0; k8 < 2; k8++)
          acc[mi][ni] = MFMA_BF16(afP[mi][k8], bfv[ni][k8], acc[mi][ni], 0, 0, 0);
    __builtin_amdgcn_s_setprio(0);
    if (wv == 0) {
      #pragma unroll
      for (int mi = 0; mi < 4; mi++)
        #pragma unroll
        for (int k8 = 0; k8 < 2; k8++)
          accSum[mi] = MFMA_BF16(afP[mi][k8], ones, accSum[mi], 0, 0, 0);
    }
    LGKM0();
    SBAR();
  }

  if (wv == 0 && lr == 0) {
    #pragma unroll
    for (int mi = 0; mi < 4; mi++)
      #pragma unroll
      for (int r = 0; r < 4; r++)
        rsl[mi * 16 + lq * 4 + r] = accSum[mi][r];
  }
  LGKM0();
  SBAR();
  #pragma unroll
  for (int mi = 0; mi < 4; mi++) {
    float iv[4];
    #pragma unroll
    for (int r = 0; r < 4; r++) iv[r] = 1.0f / rsl[mi * 16 + lq * 4 + r];
    #pragma unroll
    for (int ni = 0; ni < 4; ni++) {
      #pragma unroll
      for (int r = 0; r < 4; r++) {
        const int gt = t0 + mi * 16 + lq * 4 + r;
        const int ge = eh * 512 + wv * 64 + ni * 16 + lr;
        const long long idx = ((long long)gt * 4 + bz) * 1024 + ge;
        hrb[idx] = f2u(acc[mi][ni][r] * iv[r] * u2f(rbf[idx]));
      }
    }
  }
}

// ---------------------------------------------------------------- launch
extern "C" void kernel_launch(void* const* d_in, const int* in_sizes, int n_in,
                              void* d_out, int out_size, void* d_ws, size_t ws_size,
                              hipStream_t stream)
{
  (void)in_sizes; (void)n_in; (void)out_size; (void)ws_size;
  const float* query = (const float*)d_in[0];
  const float* key   = (const float*)d_in[1];
  const float* Wq    = (const float*)d_in[2];
  const float* bq    = (const float*)d_in[3];
  const float* Wk    = (const float*)d_in[4];
  const float* bk    = (const float*)d_in[5];
  const float* Wv    = (const float*)d_in[6];
  const float* bv    = (const float*)d_in[7];
  const float* Wh    = (const float*)d_in[8];
  const float* bh    = (const float*)d_in[9];
  const float* gamma = (const float*)d_in[10];
  const float* beta  = (const float*)d_in[11];
  float* out = (float*)d_out;

  char* p = (char*)d_ws;
  auto take = [&](size_t bytes) -> char* {
    char* r = p; p += (bytes + 255) & ~(size_t)255; return r;
  };
  unsigned short* qbf = (unsigned short*)take(8192ULL * 1024 * 2); // query bf16 (T*B,E)
  unsigned short* kbr = (unsigned short*)take(8192ULL * 1024 * 2); // key bf16 [B][S][E]
  unsigned short* Wqb = (unsigned short*)take(2176ULL * 1024 * 2);
  unsigned short* Wkb = (unsigned short*)take(128ULL  * 1024 * 2);
  unsigned short* Wvb = (unsigned short*)take(1024ULL * 1024 * 2);
  unsigned short* Whb = (unsigned short*)take(1024ULL * 1024 * 2);
  unsigned short* ub  = (unsigned short*)take(8192ULL * 1024 * 2); // u gate bf16
  unsigned short* rbf = (unsigned short*)take(8192ULL * 1024 * 2); // r bf16
  unsigned short* qpj = (unsigned short*)take(8192ULL * 128 * 2);  // q (T,B,Z)
  unsigned short* kpj = (unsigned short*)take(8192ULL * 128 * 2);  // k [B][S][Z]
  unsigned short* vT  = (unsigned short*)take(4ULL * 1024 * 2048 * 2); // v^T [B][E][S]
  unsigned short* hrb = (unsigned short*)take(8192ULL * 1024 * 2); // h*r bf16

  dim3 blk(256);
  dim3 gblk(512);
  // 1: all casts, one dispatch
  cast_all<<<20736, blk, 0, stream>>>(query, key, Wq, Wk, Wv, Wh,
      qbf, kbr, Wqb, Wkb, Wvb, Whb);
  // 2: g0 + g2 + both N=128 projections, one dispatch (576 blocks)
  mega<<<576, gblk, 0, stream>>>(qbf, Wqb, kbr, Wvb, Wkb,
      bq, bk, bv, gamma, beta, (float*)ub, rbf, vT, qpj, kpj);
  // 3: fused attention: hr = softmax(q k^T * scale) @ V * r
  attn_fused<<<dim3(2, 32, 4), gblk, 0, stream>>>(qpj, kpj, vT, rbf, hrb);
  // 4: out = query + u * (tanh(hr @ Wh^T + bh) - query)
  gemm_g5<<<dim3(32, 8, 1), gblk, 0, stream>>>(hrb, 1024, Whb, 1024, 1024,
      bh, out, ub, query);
}